// Round 13
// baseline (360.815 us; speedup 1.0000x reference)
//
#include <hip/hip_runtime.h>
#include <stdint.h>

#define NN 10000
#define NE 160000

typedef short short8 __attribute__((ext_vector_type(8)));
typedef float f32x4 __attribute__((ext_vector_type(4)));

// ---------- bf16 helpers (internal staging format; I/O is f32) ----------
__device__ __forceinline__ float bf2f(unsigned short u) {
    return __uint_as_float(((uint32_t)u) << 16);
}
__device__ __forceinline__ float bflo(uint32_t u) { return __uint_as_float(u << 16); }
__device__ __forceinline__ float bfhi(uint32_t u) { return __uint_as_float(u & 0xffff0000u); }
__device__ __forceinline__ unsigned short f2bf(float f) {
    uint32_t u = __float_as_uint(f);
    u += 0x7fffu + ((u >> 16) & 1u);   // RNE
    return (unsigned short)(u >> 16);
}
__device__ __forceinline__ uint32_t pack2(float lo, float hi) {
    return (uint32_t)f2bf(lo) | ((uint32_t)f2bf(hi) << 16);
}
__device__ __forceinline__ float silu2(float x) {
    return 1.679177f * x / (1.f + __expf(-x));
}

// ---------------------------------------------------------------------------
// k_pre (R8): fused preprocessing — wmlp (bid 0) | wup (1..64) | w4t (65..192)
// | zero counts (193..232). All outputs independent; saves 3 launches.
// ---------------------------------------------------------------------------
__global__ __launch_bounds__(256) void k_pre(const float* __restrict__ W1,
                                             const float* __restrict__ W2,
                                             const float* __restrict__ W3,
                                             const float* __restrict__ Wu0,
                                             const float* __restrict__ Wu1,
                                             const float* __restrict__ W4,
                                             unsigned short* __restrict__ w1Tp,
                                             unsigned short* __restrict__ w2T,
                                             unsigned short* __restrict__ w3T,
                                             unsigned short* __restrict__ w0T,
                                             unsigned short* __restrict__ w1T,
                                             unsigned short* __restrict__ w4T,
                                             int* __restrict__ counts) {
    int bid = blockIdx.x, t = threadIdx.x;
    if (bid == 0) {
        for (int i = t; i < 2048; i += 256) {
            int jj = i >> 5, k = i & 31;
            w1Tp[i] = (k < 8) ? f2bf(W1[k * 64 + jj] * 0.3535533905932738f) : 0;
        }
        for (int i = t; i < 4096; i += 256) {
            int jj = i >> 6, k = i & 63;
            w2T[i] = f2bf(W2[k * 64 + jj] * 0.125f);
            w3T[i] = f2bf(W3[k * 64 + jj] * 0.125f);
        }
    } else if (bid < 65) {
        const float s = 0.08838834764831845f;
        for (int i = t + (bid - 1) * 256; i < 16384; i += 256 * 64) {
            int u = i >> 7, v = i & 127;
            w0T[v * 128 + u] = f2bf(Wu0[i] * s);
            w1T[v * 128 + u] = f2bf(Wu1[i] * s);
        }
    } else if (bid < 193) {
        int idx = (bid - 65) * 256 + t;   // 32768
        int k = idx >> 9, c = idx & 511;
        w4T[c * 64 + k] = f2bf(W4[idx]);
    } else {
        int i = (bid - 193) * 256 + t;
        if (i < NN) counts[i] = 0;
    }
}

// ---------------------------------------------------------------------------
// k_prep2 (R8): prep (bid<5000) + edge histogram (bid>=5000). counts zeroed
// by k_pre (strictly earlier in stream). Saves 1 launch.
// ---------------------------------------------------------------------------
__global__ __launch_bounds__(256) void k_prep2(const float* __restrict__ nf,
                                               const int* __restrict__ ei,
                                               unsigned short* __restrict__ x0b,
                                               unsigned short* __restrict__ x1b,
                                               int* __restrict__ counts) {
    int bid = blockIdx.x;
    if (bid < 5000) {
        int idx = bid * 256 + threadIdx.x;     // 1,280,000
        int n = idx >> 7, u = idx & 127;
        const float* row = nf + (size_t)n * 512;
        x0b[(size_t)n * 128 + u] = f2bf(row[u]);
        const float* p = row + 128 + u * 3;
        x1b[(size_t)n * 128 + u]                = f2bf(p[0]);
        x1b[1280000 + (size_t)n * 128 + u]      = f2bf(p[1]);
        x1b[2560000 + (size_t)n * 128 + u]      = f2bf(p[2]);
    } else {
        int e = (bid - 5000) * 256 + threadIdx.x;
        if (e < NE) atomicAdd(&counts[ei[NE + e]], 1);
    }
}

// ---------------------------------------------------------------------------
// k_upg (MFMA): y0 = x0 @ W0, y1[m] = x1[m] @ W1.
// xw[n]: [y0 (128) | y1 m-major: 128 + m*128 + v]
// ---------------------------------------------------------------------------
__global__ __launch_bounds__(256) void k_upg(const unsigned short* __restrict__ x0b,
                                             const unsigned short* __restrict__ x1b,
                                             const unsigned short* __restrict__ w0T,
                                             const unsigned short* __restrict__ w1T,
                                             float* __restrict__ xw) {
    int wave = threadIdx.x >> 6, lane = threadIdx.x & 63;
    int wid = blockIdx.x * 4 + wave;              // 1250
    if (wid >= 1250) return;
    int tile = wid >> 1, half = wid & 1;
    int n0 = tile * 16;
    int lm = lane & 15, lq = lane >> 4;

    uint4 A0[4], A1[3][4];
    const unsigned short* a0r = x0b + (size_t)(n0 + lm) * 128 + lq * 8;
#pragma unroll
    for (int kf = 0; kf < 4; ++kf) A0[kf] = *(const uint4*)(a0r + kf * 32);
#pragma unroll
    for (int m = 0; m < 3; ++m) {
        const unsigned short* a1r = x1b + 1280000 * (size_t)m + (size_t)(n0 + lm) * 128 + lq * 8;
#pragma unroll
        for (int kf = 0; kf < 4; ++kf) A1[m][kf] = *(const uint4*)(a1r + kf * 32);
    }

    for (int vq = 0; vq < 4; ++vq) {
        int vt = half * 4 + vq;
        const unsigned short* b0r = w0T + (vt * 16 + lm) * 128 + lq * 8;
        const unsigned short* b1r = w1T + (vt * 16 + lm) * 128 + lq * 8;
        f32x4 acc0 = {0.f, 0.f, 0.f, 0.f};
#pragma unroll
        for (int kf = 0; kf < 4; ++kf) {
            short8 b = __builtin_bit_cast(short8, *(const uint4*)(b0r + kf * 32));
            acc0 = __builtin_amdgcn_mfma_f32_16x16x32_bf16(
                __builtin_bit_cast(short8, A0[kf]), b, acc0, 0, 0, 0);
        }
        f32x4 acc1[3];
#pragma unroll
        for (int m = 0; m < 3; ++m) acc1[m] = (f32x4){0.f, 0.f, 0.f, 0.f};
#pragma unroll
        for (int kf = 0; kf < 4; ++kf) {
            short8 b = __builtin_bit_cast(short8, *(const uint4*)(b1r + kf * 32));
#pragma unroll
            for (int m = 0; m < 3; ++m)
                acc1[m] = __builtin_amdgcn_mfma_f32_16x16x32_bf16(
                    __builtin_bit_cast(short8, A1[m][kf]), b, acc1[m], 0, 0, 0);
        }
        int col = vt * 16 + lm;
#pragma unroll
        for (int r = 0; r < 4; ++r) {
            float* o = xw + (size_t)(n0 + lq * 4 + r) * 512;
            o[col] = acc0[r];
            o[128 + col] = acc1[0][r];
            o[256 + col] = acc1[1][r];
            o[384 + col] = acc1[2][r];
        }
    }
}

// ---------------------------------------------------------------------------
// K2 (MFMA): edge MLP stages 1-3 -> h3 (NE x 64 bf16).
// v2 (R3): one 16-edge tile per wave; grid 2500 blocks (occupancy fix).
// ---------------------------------------------------------------------------
__global__ __launch_bounds__(256) void k_mlp(const float* __restrict__ ef,
                                             const unsigned short* __restrict__ w1Tp,
                                             const unsigned short* __restrict__ w2T,
                                             const unsigned short* __restrict__ w3T,
                                             unsigned short* __restrict__ h3w) {
    __shared__ __align__(16) unsigned short hs_all[4][16 * 72];
    int wave = threadIdx.x >> 6, lane = threadIdx.x & 63;
    int lm = lane & 15, lq = lane >> 4;
    int e0 = blockIdx.x * 64 + wave * 16;          // 16 edges per wave
    unsigned short* h = hs_all[wave];
    unsigned short* hrow = h + lm * 72;

    // stage 1: K=32 (8 real, zero-padded)
    uint4 A1[4];
#pragma unroll
    for (int mt = 0; mt < 4; ++mt)
        A1[mt] = *(const uint4*)(w1Tp + (mt * 16 + lm) * 32 + lq * 8);
    uint4 b = {0, 0, 0, 0};
    if (lq == 0) {
        const float4* p = (const float4*)(ef + (size_t)(e0 + lm) * 8);
        float4 x = p[0], y = p[1];
        b.x = pack2(x.x, x.y); b.y = pack2(x.z, x.w);
        b.z = pack2(y.x, y.y); b.w = pack2(y.z, y.w);
    }
    short8 bb = __builtin_bit_cast(short8, b);
#pragma unroll
    for (int mt = 0; mt < 4; ++mt) {
        f32x4 acc = {0.f, 0.f, 0.f, 0.f};
        acc = __builtin_amdgcn_mfma_f32_16x16x32_bf16(
            __builtin_bit_cast(short8, A1[mt]), bb, acc, 0, 0, 0);
        uint2 v;
        v.x = pack2(silu2(acc[0]), silu2(acc[1]));
        v.y = pack2(silu2(acc[2]), silu2(acc[3]));
        *(uint2*)(hrow + mt * 16 + lq * 4) = v;
    }

    // stage 2: K=64
    uint4 A2[4][2];
#pragma unroll
    for (int mt = 0; mt < 4; ++mt)
#pragma unroll
        for (int kf = 0; kf < 2; ++kf)
            A2[mt][kf] = *(const uint4*)(w2T + (mt * 16 + lm) * 64 + kf * 32 + lq * 8);
    {
        short8 B0 = __builtin_bit_cast(short8, *(const uint4*)(hrow + lq * 8));
        short8 B1 = __builtin_bit_cast(short8, *(const uint4*)(hrow + 32 + lq * 8));
#pragma unroll
        for (int mt = 0; mt < 4; ++mt) {
            f32x4 acc = {0.f, 0.f, 0.f, 0.f};
            acc = __builtin_amdgcn_mfma_f32_16x16x32_bf16(
                __builtin_bit_cast(short8, A2[mt][0]), B0, acc, 0, 0, 0);
            acc = __builtin_amdgcn_mfma_f32_16x16x32_bf16(
                __builtin_bit_cast(short8, A2[mt][1]), B1, acc, 0, 0, 0);
            uint2 v;
            v.x = pack2(silu2(acc[0]), silu2(acc[1]));
            v.y = pack2(silu2(acc[2]), silu2(acc[3]));
            *(uint2*)(hrow + mt * 16 + lq * 4) = v;
        }
    }

    // stage 3: K=64
    uint4 A3[4][2];
#pragma unroll
    for (int mt = 0; mt < 4; ++mt)
#pragma unroll
        for (int kf = 0; kf < 2; ++kf)
            A3[mt][kf] = *(const uint4*)(w3T + (mt * 16 + lm) * 64 + kf * 32 + lq * 8);
    {
        short8 B0 = __builtin_bit_cast(short8, *(const uint4*)(hrow + lq * 8));
        short8 B1 = __builtin_bit_cast(short8, *(const uint4*)(hrow + 32 + lq * 8));
#pragma unroll
        for (int mt = 0; mt < 4; ++mt) {
            f32x4 acc = {0.f, 0.f, 0.f, 0.f};
            acc = __builtin_amdgcn_mfma_f32_16x16x32_bf16(
                __builtin_bit_cast(short8, A3[mt][0]), B0, acc, 0, 0, 0);
            acc = __builtin_amdgcn_mfma_f32_16x16x32_bf16(
                __builtin_bit_cast(short8, A3[mt][1]), B1, acc, 0, 0, 0);
            uint2 v;
            v.x = pack2(silu2(acc[0]), silu2(acc[1]));
            v.y = pack2(silu2(acc[2]), silu2(acc[3]));
            *(uint2*)(hrow + mt * 16 + lq * 4) = v;
        }
    }

    // flush: 16 rows x 64 shorts = 2 KB per wave; 2 coalesced 16B chunks/lane.
#pragma unroll
    for (int q = 0; q < 2; ++q) {
        int c = lane + q * 64;                 // chunk 0..127
        int row = c >> 3, col = (c & 7) * 8;
        *(uint4*)(h3w + (size_t)(e0 + row) * 64 + col) =
            *(const uint4*)(h + row * 72 + col);
    }
}

// ---------------------------------------------------------------------------
// K3: CSR build by receiver (scan -> fill); hist fused into k_prep2.
// ---------------------------------------------------------------------------
__global__ __launch_bounds__(1024) void k_scan(const int* __restrict__ counts,
                                               int* __restrict__ offs,
                                               int* __restrict__ cursor) {
    __shared__ int sums[1024];
    int t = threadIdx.x;
    int base = t * 10;
    int s = 0;
    for (int i = 0; i < 10; ++i) {
        int idx = base + i;
        if (idx < NN) s += counts[idx];
    }
    sums[t] = s;
    __syncthreads();
    for (int d = 1; d < 1024; d <<= 1) {
        int v = (t >= d) ? sums[t - d] : 0;
        __syncthreads();
        if (t >= d) sums[t] += v;
        __syncthreads();
    }
    int run = (t == 0) ? 0 : sums[t - 1];
    for (int i = 0; i < 10; ++i) {
        int idx = base + i;
        if (idx < NN) {
            offs[idx] = run;
            cursor[idx] = run;
            run += counts[idx];
        }
    }
    if (t == 0) offs[NN] = NE;
}
__global__ void k_fill(const int* __restrict__ ei, int* __restrict__ cursor,
                       int* __restrict__ elist) {
    int e = blockIdx.x * 256 + threadIdx.x;
    if (e < NE) {
        int slot = atomicAdd(&cursor[ei[NE + e]], 1);
        elist[slot] = e;
    }
}
// k_gather: resolve per-slot sender + edge_attrs (after k_upg: eis/eap alias
// the x0b/x1b head region, dead once k_upg completes).
__global__ void k_gather(const int* __restrict__ ei, const float* __restrict__ ea,
                         const int* __restrict__ elist,
                         int* __restrict__ eis, float4* __restrict__ eap) {
    int i = blockIdx.x * 256 + threadIdx.x;
    if (i < NE) {
        int e = elist[i];
        eis[i] = ei[e];
        eap[i] = *(const float4*)(ea + (size_t)e * 4);
    }
}

// k_wt2: out-weight transpose (after k_upg: woT aliases x0b head).
__global__ void k_wt2(const float* __restrict__ Wo0, const float* __restrict__ Wo1,
                      unsigned short* __restrict__ woT0, unsigned short* __restrict__ woT1) {
    int idx = blockIdx.x * 256 + threadIdx.x;   // 32768
    int u = idx >> 7, v = idx & 127;
    woT0[v * 256 + u] = f2bf(Wo0[idx]);
    woT1[v * 256 + u] = f2bf(Wo1[idx]);
}

// ---------------------------------------------------------------------------
// k_msg2 (v6, FUSED tpw, cliff-corrected): TP + reduce with on-the-fly
// W = (h3 . W4)/8 via MFMA. Third fusion attempt; fixes both prior cliffs:
//   R4 (148us): f32 wl = 33.8KB LDS -> 4 blocks/CU, 29% occ.  -> bf16 wl
//     [4][16][130] = 16.6KB (R5-verified staging values; read-side
//     conflict-free: row stride 65 words).
//   R5 (225us): 64-thr blocks + launch_bounds(64,4) -> 64-VGPR cap -> 300MB
//     spill.  -> 256-thr blocks, no min-wave hint, A-frags loaded per-mt
//     (drops the 32-VGPR preload; w4T is L2-hot, most blocks run 1 chunk).
// TP loop bodies byte-equal to R4's verified ones except wl is read as
// packed bf16 (bflo/bfhi — exactly how the standalone kernel read tpw).
// Per-lane accumulation order unchanged -> absmax 0.03125 expected.
// ---------------------------------------------------------------------------
__global__ __launch_bounds__(256) void k_msg2(const float* __restrict__ xw,
                                              const unsigned short* __restrict__ h3w,
                                              const unsigned short* __restrict__ w4T,
                                              const int* __restrict__ eis,
                                              const float4* __restrict__ eap,
                                              const int* __restrict__ offs,
                                              const int* __restrict__ elist,
                                              unsigned short* __restrict__ msgb) {
    __shared__ __align__(8) unsigned short wl_all[4][16][130];   // 16,640 B
    int n = blockIdx.x, t = threadIdx.x;
    int j = t >> 6, lw = t & 63;
    int lm = lw & 15, lq = lw >> 4;
    int c0 = lw * 2;
    int beg = offs[n], end = offs[n + 1];
    unsigned short (*wl)[130] = wl_all[j];
    float a0 = 0.f, a1 = 0.f, a2 = 0.f, a3 = 0.f, a4 = 0.f, a5 = 0.f;

    if (end > beg) {
        const int last = end - 1;
        const unsigned short* aw = w4T + (size_t)(j * 128 + lm) * 64 + lq * 8;

        for (int cbeg = beg; cbeg < end; cbeg += 16) {
            // ---- stage W for edges cbeg..cbeg+15 via MFMA -> LDS (bf16) ----
            int slot = cbeg + lm;
            slot = slot <= last ? slot : last;
            int esrc = elist[slot];
            const unsigned short* hr = h3w + (size_t)esrc * 64 + lq * 8;
            short8 B0 = __builtin_bit_cast(short8, *(const uint4*)(hr));
            short8 B1 = __builtin_bit_cast(short8, *(const uint4*)(hr + 32));
#pragma unroll
            for (int mt = 0; mt < 8; ++mt) {
                uint4 a0r = *(const uint4*)(aw + mt * 1024);
                uint4 a1r = *(const uint4*)(aw + mt * 1024 + 32);
                f32x4 acc = {0.f, 0.f, 0.f, 0.f};
                acc = __builtin_amdgcn_mfma_f32_16x16x32_bf16(
                    __builtin_bit_cast(short8, a0r), B0, acc, 0, 0, 0);
                acc = __builtin_amdgcn_mfma_f32_16x16x32_bf16(
                    __builtin_bit_cast(short8, a1r), B1, acc, 0, 0, 0);
                uint2 v;
                v.x = pack2(acc[0] * 0.125f, acc[1] * 0.125f);
                v.y = pack2(acc[2] * 0.125f, acc[3] * 0.125f);
                *(uint2*)&wl[lm][mt * 16 + lq * 4] = v;
            }
            // same-wave ds_write -> ds_read: compiler inserts lgkmcnt.

            int cend = cbeg + 16 < end ? cbeg + 16 : end;
            if (j == 0) {
                for (int g = cbeg; g < cend; g += 8) {
                    int s_[8]; float wa[8], wb[8], ey[8]; float2 x[8];
#pragma unroll
                    for (int k = 0; k < 8; ++k) {
                        int idx = g + k;
                        int cl = idx <= last ? idx : last;
                        s_[k] = eis[cl];
                    }
#pragma unroll
                    for (int k = 0; k < 8; ++k) {
                        int idx = g + k;
                        int cl = idx <= last ? idx : last;
                        int e = idx - cbeg;
                        uint32_t w = *(const uint32_t*)&wl[e][c0];
                        wa[k] = idx <= last ? bflo(w) : 0.f;
                        wb[k] = idx <= last ? bfhi(w) : 0.f;
                        ey[k] = eap[cl].x;
                        x[k] = *(const float2*)(xw + (size_t)s_[k] * 512 + c0);
                    }
#pragma unroll
                    for (int k = 0; k < 8; ++k) {
                        a0 += wa[k] * x[k].x * ey[k];
                        a1 += wb[k] * x[k].y * ey[k];
                    }
                }
            } else if (j == 1) {
                for (int g = cbeg; g < cend; g += 8) {
                    int s_[8]; float wa[8], wb[8], ex[8], ey[8], ez[8]; float2 x[8];
#pragma unroll
                    for (int k = 0; k < 8; ++k) {
                        int idx = g + k;
                        int cl = idx <= last ? idx : last;
                        s_[k] = eis[cl];
                    }
#pragma unroll
                    for (int k = 0; k < 8; ++k) {
                        int idx = g + k;
                        int cl = idx <= last ? idx : last;
                        int e = idx - cbeg;
                        uint32_t w = *(const uint32_t*)&wl[e][c0];
                        wa[k] = idx <= last ? bflo(w) : 0.f;
                        wb[k] = idx <= last ? bfhi(w) : 0.f;
                        float4 ev = eap[cl];
                        ex[k] = ev.y; ey[k] = ev.z; ez[k] = ev.w;
                        x[k] = *(const float2*)(xw + (size_t)s_[k] * 512 + c0);
                    }
#pragma unroll
                    for (int k = 0; k < 8; ++k) {
                        float ta = wa[k] * x[k].x, tb = wb[k] * x[k].y;
                        a0 += ta * ex[k]; a1 += ta * ey[k]; a2 += ta * ez[k];
                        a3 += tb * ex[k]; a4 += tb * ey[k]; a5 += tb * ez[k];
                    }
                }
            } else if (j == 2) {
                for (int g = cbeg; g < cend; g += 8) {
                    int s_[8]; float wa[8], wb[8], ey[8];
                    float2 x0[8], x1[8], x2[8];
#pragma unroll
                    for (int k = 0; k < 8; ++k) {
                        int idx = g + k;
                        int cl = idx <= last ? idx : last;
                        s_[k] = eis[cl];
                    }
#pragma unroll
                    for (int k = 0; k < 8; ++k) {
                        int idx = g + k;
                        int cl = idx <= last ? idx : last;
                        int e = idx - cbeg;
                        uint32_t w = *(const uint32_t*)&wl[e][c0];
                        wa[k] = idx <= last ? bflo(w) : 0.f;
                        wb[k] = idx <= last ? bfhi(w) : 0.f;
                        ey[k] = eap[cl].x;
                        const float* xr = xw + (size_t)s_[k] * 512 + c0;
                        x0[k] = *(const float2*)(xr + 128);
                        x1[k] = *(const float2*)(xr + 256);
                        x2[k] = *(const float2*)(xr + 384);
                    }
#pragma unroll
                    for (int k = 0; k < 8; ++k) {
                        float f0 = wa[k] * ey[k], f1 = wb[k] * ey[k];
                        a0 += f0 * x0[k].x; a1 += f0 * x1[k].x; a2 += f0 * x2[k].x;
                        a3 += f1 * x0[k].y; a4 += f1 * x1[k].y; a5 += f1 * x2[k].y;
                    }
                }
            } else {
                for (int g = cbeg; g < cend; g += 8) {
                    int s_[8]; float wa[8], wb[8], ex[8], ey[8], ez[8];
                    float2 x0[8], x1[8], x2[8];
#pragma unroll
                    for (int k = 0; k < 8; ++k) {
                        int idx = g + k;
                        int cl = idx <= last ? idx : last;
                        s_[k] = eis[cl];
                    }
#pragma unroll
                    for (int k = 0; k < 8; ++k) {
                        int idx = g + k;
                        int cl = idx <= last ? idx : last;
                        int e = idx - cbeg;
                        uint32_t w = *(const uint32_t*)&wl[e][c0];
                        wa[k] = idx <= last ? bflo(w) : 0.f;
                        wb[k] = idx <= last ? bfhi(w) : 0.f;
                        float4 ev = eap[cl];
                        ex[k] = ev.y; ey[k] = ev.z; ez[k] = ev.w;
                        const float* xr = xw + (size_t)s_[k] * 512 + c0;
                        x0[k] = *(const float2*)(xr + 128);
                        x1[k] = *(const float2*)(xr + 256);
                        x2[k] = *(const float2*)(xr + 384);
                    }
#pragma unroll
                    for (int k = 0; k < 8; ++k) {
                        float dta = x0[k].x * ex[k] + x1[k].x * ey[k] + x2[k].x * ez[k];
                        float dtb = x0[k].y * ex[k] + x1[k].y * ey[k] + x2[k].y * ez[k];
                        a0 += wa[k] * dta * 0.5773502691896258f;
                        a1 += wb[k] * dtb * 0.5773502691896258f;
                    }
                }
            }
        }
    }

    unsigned short* mr = msgb + (size_t)n * 1024;
    if (j == 0) {
        *(uint32_t*)(mr + c0) = pack2(a0, a1);
    } else if (j == 1) {
        *(uint32_t*)(mr + 256 + c0)       = pack2(a0, a3);
        *(uint32_t*)(mr + 256 + 256 + c0) = pack2(a1, a4);
        *(uint32_t*)(mr + 256 + 512 + c0) = pack2(a2, a5);
    } else if (j == 2) {
        *(uint32_t*)(mr + 256 + 128 + c0)       = pack2(a0, a3);
        *(uint32_t*)(mr + 256 + 256 + 128 + c0) = pack2(a1, a4);
        *(uint32_t*)(mr + 256 + 512 + 128 + c0) = pack2(a2, a5);
    } else {
        *(uint32_t*)(mr + 128 + c0) = pack2(a0, a1);
    }
}

// ---------------------------------------------------------------------------
// k_out (R8, fused out0+out1): same 157-block grid, bodies unchanged; all
// A-loads (8 + 24 uint4) issued up front so the two serial A-latency
// exposures overlap.
// ---------------------------------------------------------------------------
__global__ __launch_bounds__(256) void k_out(const unsigned short* __restrict__ msgb,
                                             const unsigned short* __restrict__ woT0,
                                             const unsigned short* __restrict__ woT1,
                                             float* __restrict__ out) {
    int wave = threadIdx.x >> 6, lane = threadIdx.x & 63;
    int wid = blockIdx.x * 4 + wave;
    if (wid >= NN / 16) return;
    int n0 = wid * 16;
    int lm = lane & 15, lq = lane >> 4;
    const unsigned short* ar = msgb + (size_t)(n0 + lm) * 1024 + lq * 8;

    uint4 A0[8];
#pragma unroll
    for (int kf = 0; kf < 8; ++kf) A0[kf] = *(const uint4*)(ar + kf * 32);
    uint4 A1[3][8];
#pragma unroll
    for (int m = 0; m < 3; ++m)
#pragma unroll
        for (int kf = 0; kf < 8; ++kf)
            A1[m][kf] = *(const uint4*)(ar + 256 + m * 256 + kf * 32);

    // ---- out0: o0 = msg0 @ Wo0 ----
    {
        const unsigned short* br = woT0 + lm * 256 + lq * 8;
        float* ob = out + (size_t)n0 * 512;
        for (int vt = 0; vt < 8; ++vt) {
            f32x4 acc = {0.f, 0.f, 0.f, 0.f};
#pragma unroll
            for (int kf = 0; kf < 8; ++kf) {
                uint4 b = *(const uint4*)(br + vt * 16 * 256 + kf * 32);
                acc = __builtin_amdgcn_mfma_f32_16x16x32_bf16(
                    __builtin_bit_cast(short8, A0[kf]), __builtin_bit_cast(short8, b), acc, 0, 0, 0);
            }
#pragma unroll
            for (int r = 0; r < 4; ++r)
                ob[(size_t)(lq * 4 + r) * 512 + vt * 16 + lm] = acc[r] * 0.00625f;
        }
    }

    // ---- out1: 3 GEMMs sharing B = woT1 -> out[n][128 + v*3 + m] ----
    {
        const unsigned short* br = woT1 + lm * 256 + lq * 8;
        float* ob = out + (size_t)n0 * 512 + 128;
        for (int vt = 0; vt < 8; ++vt) {
            f32x4 acc[3];
#pragma unroll
            for (int m = 0; m < 3; ++m) acc[m] = (f32x4){0.f, 0.f, 0.f, 0.f};
#pragma unroll
            for (int kf = 0; kf < 8; ++kf) {
                uint4 braw = *(const uint4*)(br + vt * 16 * 256 + kf * 32);
                short8 b = __builtin_bit_cast(short8, braw);
#pragma unroll
                for (int m = 0; m < 3; ++m)
                    acc[m] = __builtin_amdgcn_mfma_f32_16x16x32_bf16(
                        __builtin_bit_cast(short8, A1[m][kf]), b, acc[m], 0, 0, 0);
            }
            int vb = (vt * 16 + lm) * 3;
#pragma unroll
            for (int r = 0; r < 4; ++r) {
                float* o = ob + (size_t)(lq * 4 + r) * 512 + vb;
                o[0] = acc[0][r] * 0.00625f;
                o[1] = acc[1][r] * 0.00625f;
                o[2] = acc[2][r] * 0.00625f;
            }
        }
    }
}

// ---------------------------------------------------------------------------
extern "C" void kernel_launch(void* const* d_in, const int* in_sizes, int n_in,
                              void* d_out, int out_size, void* d_ws, size_t ws_size,
                              hipStream_t stream) {
    const float* nf  = (const float*)d_in[0];
    const float* ea  = (const float*)d_in[1];
    const float* ef  = (const float*)d_in[2];
    const int*   ei  = (const int*)d_in[3];
    const float* Wu0 = (const float*)d_in[4];
    const float* Wu1 = (const float*)d_in[5];
    const float* W1  = (const float*)d_in[6];
    const float* W2  = (const float*)d_in[7];
    const float* W3  = (const float*)d_in[8];
    const float* W4  = (const float*)d_in[9];
    const float* Wo0 = (const float*)d_in[10];
    const float* Wo1 = (const float*)d_in[11];
    float* out = (float*)d_out;
    char* ws = (char*)d_ws;

    // Layout (R4-verified): tpw is GONE (fused into k_msg2); h3 stays live
    // through k_msg2. Head region [0, 163.84M) hosts, in stream order:
    //   x0b/x1b (k_prep2/k_upg, dead after k_upg)
    //   woT0/woT1 (k_wt2), eap/eis (k_gather) — both launched after k_upg.
    //   xw [163.84M) h3 [184.32M) msg [204.8M) w4T [225.28M) CSR ints, weights.
    unsigned short* x0b  = (unsigned short*)ws;                 // 2.56 MB
    unsigned short* x1b  = (unsigned short*)(ws + 2560000);     // 7.68 MB
    unsigned short* woT0 = (unsigned short*)ws;                           // 64KB
    unsigned short* woT1 = (unsigned short*)(ws + 65536);                 // 64KB
    float4*         eap  = (float4*)(ws + 131072);                        // NE*16B
    int*            eis  = (int*)(ws + 131072 + 2560000);                 // NE*4B
    float*          xw   = (float*)(ws + 163840000);
    unsigned short* h3w  = (unsigned short*)(ws + 184320000);
    unsigned short* msgb = (unsigned short*)(ws + 204800000);
    unsigned short* w4T  = (unsigned short*)(ws + 225280000);
    int* ib     = (int*)(ws + 225280000 + 65536);
    int* counts = ib;                        // NN
    int* offs   = ib + 10240;                // NN+1
    int* cursor = ib + 20480;                // NN
    int* elist  = ib + 30720;                // NE
    unsigned short* w1Tp = (unsigned short*)(ws + 226108416);          // 64x32
    unsigned short* w2T  = (unsigned short*)(ws + 226108416 + 4096);   // 64x64
    unsigned short* w3T  = (unsigned short*)(ws + 226108416 + 12288);  // 64x64
    unsigned short* w0T  = (unsigned short*)(ws + 226128896);          // 128x128 (32KB)
    unsigned short* w1T  = (unsigned short*)(ws + 226161664);          // 128x128 (32KB)

    k_pre   <<<233, 256, 0, stream>>>(W1, W2, W3, Wu0, Wu1, W4,
                                      w1Tp, w2T, w3T, w0T, w1T, w4T, counts);
    k_prep2 <<<5625, 256, 0, stream>>>(nf, ei, x0b, x1b, counts);
    k_upg   <<<313, 256, 0, stream>>>(x0b, x1b, w0T, w1T, xw);
    k_mlp   <<<2500, 256, 0, stream>>>(ef, w1Tp, w2T, w3T, h3w);
    k_scan  <<<1, 1024, 0, stream>>>(counts, offs, cursor);
    k_fill  <<<625, 256, 0, stream>>>(ei, cursor, elist);
    k_wt2   <<<128, 256, 0, stream>>>(Wo0, Wo1, woT0, woT1);   // x0b/x1b dead
    k_gather<<<625, 256, 0, stream>>>(ei, ea, elist, eis, eap);
    k_msg2  <<<NN, 256, 0, stream>>>(xw, h3w, w4T, eis, eap, offs, elist, msgb);
    k_out   <<<157, 256, 0, stream>>>(msgb, woT0, woT1, out);
}

// Round 14
// 344.559 us; speedup vs baseline: 1.0472x; 1.0472x over previous
//
#include <hip/hip_runtime.h>
#include <stdint.h>

#define NN 10000
#define NE 160000

typedef short short8 __attribute__((ext_vector_type(8)));
typedef float f32x4 __attribute__((ext_vector_type(4)));

// ---------- bf16 helpers (internal staging format; I/O is f32) ----------
__device__ __forceinline__ float bf2f(unsigned short u) {
    return __uint_as_float(((uint32_t)u) << 16);
}
__device__ __forceinline__ float bflo(uint32_t u) { return __uint_as_float(u << 16); }
__device__ __forceinline__ float bfhi(uint32_t u) { return __uint_as_float(u & 0xffff0000u); }
__device__ __forceinline__ unsigned short f2bf(float f) {
    uint32_t u = __float_as_uint(f);
    u += 0x7fffu + ((u >> 16) & 1u);   // RNE
    return (unsigned short)(u >> 16);
}
__device__ __forceinline__ uint32_t pack2(float lo, float hi) {
    return (uint32_t)f2bf(lo) | ((uint32_t)f2bf(hi) << 16);
}
__device__ __forceinline__ float silu2(float x) {
    return 1.679177f * x / (1.f + __expf(-x));
}

// ---------------------------------------------------------------------------
// k_pre (R8): fused preprocessing — wmlp (bid 0) | wup (1..64) | w4t (65..192)
// | zero counts (193..232). All outputs independent; saves 3 launches.
// ---------------------------------------------------------------------------
__global__ __launch_bounds__(256) void k_pre(const float* __restrict__ W1,
                                             const float* __restrict__ W2,
                                             const float* __restrict__ W3,
                                             const float* __restrict__ Wu0,
                                             const float* __restrict__ Wu1,
                                             const float* __restrict__ W4,
                                             unsigned short* __restrict__ w1Tp,
                                             unsigned short* __restrict__ w2T,
                                             unsigned short* __restrict__ w3T,
                                             unsigned short* __restrict__ w0T,
                                             unsigned short* __restrict__ w1T,
                                             unsigned short* __restrict__ w4T,
                                             int* __restrict__ counts) {
    int bid = blockIdx.x, t = threadIdx.x;
    if (bid == 0) {
        for (int i = t; i < 2048; i += 256) {
            int jj = i >> 5, k = i & 31;
            w1Tp[i] = (k < 8) ? f2bf(W1[k * 64 + jj] * 0.3535533905932738f) : 0;
        }
        for (int i = t; i < 4096; i += 256) {
            int jj = i >> 6, k = i & 63;
            w2T[i] = f2bf(W2[k * 64 + jj] * 0.125f);
            w3T[i] = f2bf(W3[k * 64 + jj] * 0.125f);
        }
    } else if (bid < 65) {
        const float s = 0.08838834764831845f;
        for (int i = t + (bid - 1) * 256; i < 16384; i += 256 * 64) {
            int u = i >> 7, v = i & 127;
            w0T[v * 128 + u] = f2bf(Wu0[i] * s);
            w1T[v * 128 + u] = f2bf(Wu1[i] * s);
        }
    } else if (bid < 193) {
        int idx = (bid - 65) * 256 + t;   // 32768
        int k = idx >> 9, c = idx & 511;
        w4T[c * 64 + k] = f2bf(W4[idx]);
    } else {
        int i = (bid - 193) * 256 + t;
        if (i < NN) counts[i] = 0;
    }
}

// ---------------------------------------------------------------------------
// k_prep2 (R8): prep (bid<5000) + edge histogram (bid>=5000). counts zeroed
// by k_pre (strictly earlier in stream). Saves 1 launch.
// ---------------------------------------------------------------------------
__global__ __launch_bounds__(256) void k_prep2(const float* __restrict__ nf,
                                               const int* __restrict__ ei,
                                               unsigned short* __restrict__ x0b,
                                               unsigned short* __restrict__ x1b,
                                               int* __restrict__ counts) {
    int bid = blockIdx.x;
    if (bid < 5000) {
        int idx = bid * 256 + threadIdx.x;     // 1,280,000
        int n = idx >> 7, u = idx & 127;
        const float* row = nf + (size_t)n * 512;
        x0b[(size_t)n * 128 + u] = f2bf(row[u]);
        const float* p = row + 128 + u * 3;
        x1b[(size_t)n * 128 + u]                = f2bf(p[0]);
        x1b[1280000 + (size_t)n * 128 + u]      = f2bf(p[1]);
        x1b[2560000 + (size_t)n * 128 + u]      = f2bf(p[2]);
    } else {
        int e = (bid - 5000) * 256 + threadIdx.x;
        if (e < NE) atomicAdd(&counts[ei[NE + e]], 1);
    }
}

// ---------------------------------------------------------------------------
// k_upg (MFMA): y0 = x0 @ W0, y1[m] = x1[m] @ W1. (R9 proven)
// xw[n]: [y0 (128) | y1 m-major: 128 + m*128 + v]
// ---------------------------------------------------------------------------
__global__ __launch_bounds__(256) void k_upg(const unsigned short* __restrict__ x0b,
                                             const unsigned short* __restrict__ x1b,
                                             const unsigned short* __restrict__ w0T,
                                             const unsigned short* __restrict__ w1T,
                                             float* __restrict__ xw) {
    int wave = threadIdx.x >> 6, lane = threadIdx.x & 63;
    int wid = blockIdx.x * 4 + wave;              // 1250
    if (wid >= 1250) return;
    int tile = wid >> 1, half = wid & 1;
    int n0 = tile * 16;
    int lm = lane & 15, lq = lane >> 4;

    uint4 A0[4], A1[3][4];
    const unsigned short* a0r = x0b + (size_t)(n0 + lm) * 128 + lq * 8;
#pragma unroll
    for (int kf = 0; kf < 4; ++kf) A0[kf] = *(const uint4*)(a0r + kf * 32);
#pragma unroll
    for (int m = 0; m < 3; ++m) {
        const unsigned short* a1r = x1b + 1280000 * (size_t)m + (size_t)(n0 + lm) * 128 + lq * 8;
#pragma unroll
        for (int kf = 0; kf < 4; ++kf) A1[m][kf] = *(const uint4*)(a1r + kf * 32);
    }

    for (int vq = 0; vq < 4; ++vq) {
        int vt = half * 4 + vq;
        const unsigned short* b0r = w0T + (vt * 16 + lm) * 128 + lq * 8;
        const unsigned short* b1r = w1T + (vt * 16 + lm) * 128 + lq * 8;
        f32x4 acc0 = {0.f, 0.f, 0.f, 0.f};
#pragma unroll
        for (int kf = 0; kf < 4; ++kf) {
            short8 b = __builtin_bit_cast(short8, *(const uint4*)(b0r + kf * 32));
            acc0 = __builtin_amdgcn_mfma_f32_16x16x32_bf16(
                __builtin_bit_cast(short8, A0[kf]), b, acc0, 0, 0, 0);
        }
        f32x4 acc1[3];
#pragma unroll
        for (int m = 0; m < 3; ++m) acc1[m] = (f32x4){0.f, 0.f, 0.f, 0.f};
#pragma unroll
        for (int kf = 0; kf < 4; ++kf) {
            short8 b = __builtin_bit_cast(short8, *(const uint4*)(b1r + kf * 32));
#pragma unroll
            for (int m = 0; m < 3; ++m)
                acc1[m] = __builtin_amdgcn_mfma_f32_16x16x32_bf16(
                    __builtin_bit_cast(short8, A1[m][kf]), b, acc1[m], 0, 0, 0);
        }
        int col = vt * 16 + lm;
#pragma unroll
        for (int r = 0; r < 4; ++r) {
            float* o = xw + (size_t)(n0 + lq * 4 + r) * 512;
            o[col] = acc0[r];
            o[128 + col] = acc1[0][r];
            o[256 + col] = acc1[1][r];
            o[384 + col] = acc1[2][r];
        }
    }
}

// ---------------------------------------------------------------------------
// K2 (MFMA): edge MLP stages 1-3 -> h3 (NE x 64 bf16).
// v2 (R3): one 16-edge tile per wave; grid 2500 blocks (occupancy fix).
// ---------------------------------------------------------------------------
__global__ __launch_bounds__(256) void k_mlp(const float* __restrict__ ef,
                                             const unsigned short* __restrict__ w1Tp,
                                             const unsigned short* __restrict__ w2T,
                                             const unsigned short* __restrict__ w3T,
                                             unsigned short* __restrict__ h3w) {
    __shared__ __align__(16) unsigned short hs_all[4][16 * 72];
    int wave = threadIdx.x >> 6, lane = threadIdx.x & 63;
    int lm = lane & 15, lq = lane >> 4;
    int e0 = blockIdx.x * 64 + wave * 16;          // 16 edges per wave
    unsigned short* h = hs_all[wave];
    unsigned short* hrow = h + lm * 72;

    // stage 1: K=32 (8 real, zero-padded)
    uint4 A1[4];
#pragma unroll
    for (int mt = 0; mt < 4; ++mt)
        A1[mt] = *(const uint4*)(w1Tp + (mt * 16 + lm) * 32 + lq * 8);
    uint4 b = {0, 0, 0, 0};
    if (lq == 0) {
        const float4* p = (const float4*)(ef + (size_t)(e0 + lm) * 8);
        float4 x = p[0], y = p[1];
        b.x = pack2(x.x, x.y); b.y = pack2(x.z, x.w);
        b.z = pack2(y.x, y.y); b.w = pack2(y.z, y.w);
    }
    short8 bb = __builtin_bit_cast(short8, b);
#pragma unroll
    for (int mt = 0; mt < 4; ++mt) {
        f32x4 acc = {0.f, 0.f, 0.f, 0.f};
        acc = __builtin_amdgcn_mfma_f32_16x16x32_bf16(
            __builtin_bit_cast(short8, A1[mt]), bb, acc, 0, 0, 0);
        uint2 v;
        v.x = pack2(silu2(acc[0]), silu2(acc[1]));
        v.y = pack2(silu2(acc[2]), silu2(acc[3]));
        *(uint2*)(hrow + mt * 16 + lq * 4) = v;
    }

    // stage 2: K=64
    uint4 A2[4][2];
#pragma unroll
    for (int mt = 0; mt < 4; ++mt)
#pragma unroll
        for (int kf = 0; kf < 2; ++kf)
            A2[mt][kf] = *(const uint4*)(w2T + (mt * 16 + lm) * 64 + kf * 32 + lq * 8);
    {
        short8 B0 = __builtin_bit_cast(short8, *(const uint4*)(hrow + lq * 8));
        short8 B1 = __builtin_bit_cast(short8, *(const uint4*)(hrow + 32 + lq * 8));
#pragma unroll
        for (int mt = 0; mt < 4; ++mt) {
            f32x4 acc = {0.f, 0.f, 0.f, 0.f};
            acc = __builtin_amdgcn_mfma_f32_16x16x32_bf16(
                __builtin_bit_cast(short8, A2[mt][0]), B0, acc, 0, 0, 0);
            acc = __builtin_amdgcn_mfma_f32_16x16x32_bf16(
                __builtin_bit_cast(short8, A2[mt][1]), B1, acc, 0, 0, 0);
            uint2 v;
            v.x = pack2(silu2(acc[0]), silu2(acc[1]));
            v.y = pack2(silu2(acc[2]), silu2(acc[3]));
            *(uint2*)(hrow + mt * 16 + lq * 4) = v;
        }
    }

    // stage 3: K=64
    uint4 A3[4][2];
#pragma unroll
    for (int mt = 0; mt < 4; ++mt)
#pragma unroll
        for (int kf = 0; kf < 2; ++kf)
            A3[mt][kf] = *(const uint4*)(w3T + (mt * 16 + lm) * 64 + kf * 32 + lq * 8);
    {
        short8 B0 = __builtin_bit_cast(short8, *(const uint4*)(hrow + lq * 8));
        short8 B1 = __builtin_bit_cast(short8, *(const uint4*)(hrow + 32 + lq * 8));
#pragma unroll
        for (int mt = 0; mt < 4; ++mt) {
            f32x4 acc = {0.f, 0.f, 0.f, 0.f};
            acc = __builtin_amdgcn_mfma_f32_16x16x32_bf16(
                __builtin_bit_cast(short8, A3[mt][0]), B0, acc, 0, 0, 0);
            acc = __builtin_amdgcn_mfma_f32_16x16x32_bf16(
                __builtin_bit_cast(short8, A3[mt][1]), B1, acc, 0, 0, 0);
            uint2 v;
            v.x = pack2(silu2(acc[0]), silu2(acc[1]));
            v.y = pack2(silu2(acc[2]), silu2(acc[3]));
            *(uint2*)(hrow + mt * 16 + lq * 4) = v;
        }
    }

    // flush: 16 rows x 64 shorts = 2 KB per wave; 2 coalesced 16B chunks/lane.
#pragma unroll
    for (int q = 0; q < 2; ++q) {
        int c = lane + q * 64;                 // chunk 0..127
        int row = c >> 3, col = (c & 7) * 8;
        *(uint4*)(h3w + (size_t)(e0 + row) * 64 + col) =
            *(const uint4*)(h + row * 72 + col);
    }
}

// ---------------------------------------------------------------------------
// K3: CSR build by receiver (scan -> fill); hist fused into k_prep2.
// ---------------------------------------------------------------------------
__global__ __launch_bounds__(1024) void k_scan(const int* __restrict__ counts,
                                               int* __restrict__ offs,
                                               int* __restrict__ cursor) {
    __shared__ int sums[1024];
    int t = threadIdx.x;
    int base = t * 10;
    int s = 0;
    for (int i = 0; i < 10; ++i) {
        int idx = base + i;
        if (idx < NN) s += counts[idx];
    }
    sums[t] = s;
    __syncthreads();
    for (int d = 1; d < 1024; d <<= 1) {
        int v = (t >= d) ? sums[t - d] : 0;
        __syncthreads();
        if (t >= d) sums[t] += v;
        __syncthreads();
    }
    int run = (t == 0) ? 0 : sums[t - 1];
    for (int i = 0; i < 10; ++i) {
        int idx = base + i;
        if (idx < NN) {
            offs[idx] = run;
            cursor[idx] = run;
            run += counts[idx];
        }
    }
    if (t == 0) offs[NN] = NE;
}
__global__ void k_fill(const int* __restrict__ ei, int* __restrict__ cursor,
                       int* __restrict__ elist) {
    int e = blockIdx.x * 256 + threadIdx.x;
    if (e < NE) {
        int slot = atomicAdd(&cursor[ei[NE + e]], 1);
        elist[slot] = e;
    }
}
// k_gather: resolve per-slot sender + edge_attrs (must run after k_tpw:
// eis/eap alias the h3 region that k_tpw still reads).
__global__ void k_gather(const int* __restrict__ ei, const float* __restrict__ ea,
                         const int* __restrict__ elist,
                         int* __restrict__ eis, float4* __restrict__ eap) {
    int i = blockIdx.x * 256 + threadIdx.x;
    if (i < NE) {
        int e = elist[i];
        eis[i] = ei[e];
        eap[i] = *(const float4*)(ea + (size_t)e * 4);
    }
}

// k_wt2: out-weight transpose (must run after k_tpw: woT aliases h3 head).
__global__ void k_wt2(const float* __restrict__ Wo0, const float* __restrict__ Wo1,
                      unsigned short* __restrict__ woT0, unsigned short* __restrict__ woT1) {
    int idx = blockIdx.x * 256 + threadIdx.x;   // 32768
    int u = idx >> 7, v = idx & 127;
    woT0[v * 256 + u] = f2bf(Wo0[idx]);
    woT1[v * 256 + u] = f2bf(Wo1[idx]);
}

// ---------------------------------------------------------------------------
// k_tpw (PERMUTED + PLANE LAYOUT): tpw is stored as 4 column-planes
//   tpwp[j][slot][128]  (j = c>>7, local col = c&127)
// so that k_msg2's wave j streams slot-consecutive 256B lines.
// tpw_perm[slot] = (h3[elist[slot]] . W4[:,c]) / 8 via MFMA (R5-verified).
// R11: exact R8 body. R9 (fine-grid re-tile, 91.7us), R10 (LDS-staged
// stores, 77.5us at 19% occ), and R4/R5/R13 (fusion into k_msg2: 148/225/
// 156us, serial staging chain) all lost to this simple split form (~69us).
// ---------------------------------------------------------------------------
__global__ __launch_bounds__(256) void k_tpw(const unsigned short* __restrict__ h3w,
                                             const unsigned short* __restrict__ w4T,
                                             const int* __restrict__ elist,
                                             unsigned short* __restrict__ tpw) {
    int wave = threadIdx.x >> 6, lane = threadIdx.x & 63;
    int e0 = blockIdx.x * 256 + wave * 64;
    int lm = lane & 15, lq = lane >> 4;
    uint4 B[4][2];
#pragma unroll
    for (int n = 0; n < 4; ++n) {
        int esrc = elist[e0 + n * 16 + lm];
#pragma unroll
        for (int k = 0; k < 2; ++k)
            B[n][k] = *(const uint4*)(h3w + (size_t)esrc * 64 + k * 32 + lq * 8);
    }
    const unsigned short* aw = w4T + lm * 64 + lq * 8;
#pragma unroll 2
    for (int m = 0; m < 32; ++m) {
        f32x4 acc0 = {0.f, 0.f, 0.f, 0.f};
        f32x4 acc1 = {0.f, 0.f, 0.f, 0.f};
        f32x4 acc2 = {0.f, 0.f, 0.f, 0.f};
        f32x4 acc3 = {0.f, 0.f, 0.f, 0.f};
#pragma unroll
        for (int k = 0; k < 2; ++k) {
            uint4 a_raw = *(const uint4*)(aw + m * 1024 + k * 32);
            short8 a = __builtin_bit_cast(short8, a_raw);
            acc0 = __builtin_amdgcn_mfma_f32_16x16x32_bf16(a, __builtin_bit_cast(short8, B[0][k]), acc0, 0, 0, 0);
            acc1 = __builtin_amdgcn_mfma_f32_16x16x32_bf16(a, __builtin_bit_cast(short8, B[1][k]), acc1, 0, 0, 0);
            acc2 = __builtin_amdgcn_mfma_f32_16x16x32_bf16(a, __builtin_bit_cast(short8, B[2][k]), acc2, 0, 0, 0);
            acc3 = __builtin_amdgcn_mfma_f32_16x16x32_bf16(a, __builtin_bit_cast(short8, B[3][k]), acc3, 0, 0, 0);
        }
        int cb = m * 16 + lq * 4;                 // global col 0..511
        int plane = cb >> 7, cl = cb & 127;
        unsigned short* pb = tpw + (size_t)plane * NE * 128 + cl;
        uint2 v;
        v.x = pack2(acc0[0] * 0.125f, acc0[1] * 0.125f);
        v.y = pack2(acc0[2] * 0.125f, acc0[3] * 0.125f);
        *(uint2*)(pb + (size_t)(e0 + 0 * 16 + lm) * 128) = v;
        v.x = pack2(acc1[0] * 0.125f, acc1[1] * 0.125f);
        v.y = pack2(acc1[2] * 0.125f, acc1[3] * 0.125f);
        *(uint2*)(pb + (size_t)(e0 + 1 * 16 + lm) * 128) = v;
        v.x = pack2(acc2[0] * 0.125f, acc2[1] * 0.125f);
        v.y = pack2(acc2[2] * 0.125f, acc2[3] * 0.125f);
        *(uint2*)(pb + (size_t)(e0 + 2 * 16 + lm) * 128) = v;
        v.x = pack2(acc3[0] * 0.125f, acc3[1] * 0.125f);
        v.y = pack2(acc3[2] * 0.125f, acc3[3] * 0.125f);
        *(uint2*)(pb + (size_t)(e0 + 3 * 16 + lm) * 128) = v;
    }
}

// ---------------------------------------------------------------------------
// k_msg2 (v3, batched-ILP, R3/R8/R11-proven, byte-identical): TP + reduce.
// ---------------------------------------------------------------------------
__global__ __launch_bounds__(256) void k_msg2(const float* __restrict__ xw,
                                              const unsigned short* __restrict__ tpw,
                                              const int* __restrict__ eis,
                                              const float4* __restrict__ eap,
                                              const int* __restrict__ offs,
                                              unsigned short* __restrict__ msgb) {
    int n = blockIdx.x, t = threadIdx.x;
    int j = t >> 6, c0 = (t & 63) * 2;
    int beg = offs[n], end = offs[n + 1];
    const unsigned short* plane = tpw + (size_t)j * NE * 128;
    float a0 = 0.f, a1 = 0.f, a2 = 0.f, a3 = 0.f, a4 = 0.f, a5 = 0.f;

    if (end > beg) {
        const int last = end - 1;
        int s[8];
#pragma unroll
        for (int k = 0; k < 8; ++k) {
            int idx = beg + k;
            s[k] = eis[idx <= last ? idx : last];
        }
        if (j == 0) {
            for (int g = beg; g < end; g += 8) {
                int sn[8];
#pragma unroll
                for (int k = 0; k < 8; ++k) {
                    int idx = g + 8 + k;
                    sn[k] = eis[idx <= last ? idx : last];
                }
                float wa[8], wb[8], ey[8];
                float2 x[8];
#pragma unroll
                for (int k = 0; k < 8; ++k) {
                    int idx = g + k;
                    int cl = idx <= last ? idx : last;
                    uint32_t w = *(const uint32_t*)(plane + (size_t)cl * 128 + c0);
                    wa[k] = idx <= last ? bflo(w) : 0.f;
                    wb[k] = idx <= last ? bfhi(w) : 0.f;
                    ey[k] = eap[cl].x;
                    x[k] = *(const float2*)(xw + (size_t)s[k] * 512 + c0);
                }
#pragma unroll
                for (int k = 0; k < 8; ++k) {
                    a0 += wa[k] * x[k].x * ey[k];
                    a1 += wb[k] * x[k].y * ey[k];
                }
#pragma unroll
                for (int k = 0; k < 8; ++k) s[k] = sn[k];
            }
        } else if (j == 1) {
            for (int g = beg; g < end; g += 8) {
                int sn[8];
#pragma unroll
                for (int k = 0; k < 8; ++k) {
                    int idx = g + 8 + k;
                    sn[k] = eis[idx <= last ? idx : last];
                }
                float wa[8], wb[8], ex[8], ey[8], ez[8];
                float2 x[8];
#pragma unroll
                for (int k = 0; k < 8; ++k) {
                    int idx = g + k;
                    int cl = idx <= last ? idx : last;
                    uint32_t w = *(const uint32_t*)(plane + (size_t)cl * 128 + c0);
                    wa[k] = idx <= last ? bflo(w) : 0.f;
                    wb[k] = idx <= last ? bfhi(w) : 0.f;
                    float4 e = eap[cl];
                    ex[k] = e.y; ey[k] = e.z; ez[k] = e.w;
                    x[k] = *(const float2*)(xw + (size_t)s[k] * 512 + c0);
                }
#pragma unroll
                for (int k = 0; k < 8; ++k) {
                    float ta = wa[k] * x[k].x, tb = wb[k] * x[k].y;
                    a0 += ta * ex[k]; a1 += ta * ey[k]; a2 += ta * ez[k];
                    a3 += tb * ex[k]; a4 += tb * ey[k]; a5 += tb * ez[k];
                }
#pragma unroll
                for (int k = 0; k < 8; ++k) s[k] = sn[k];
            }
        } else if (j == 2) {
            for (int g = beg; g < end; g += 8) {
                int sn[8];
#pragma unroll
                for (int k = 0; k < 8; ++k) {
                    int idx = g + 8 + k;
                    sn[k] = eis[idx <= last ? idx : last];
                }
                float wa[8], wb[8], ey[8];
                float2 x0[8], x1[8], x2[8];
#pragma unroll
                for (int k = 0; k < 8; ++k) {
                    int idx = g + k;
                    int cl = idx <= last ? idx : last;
                    uint32_t w = *(const uint32_t*)(plane + (size_t)cl * 128 + c0);
                    wa[k] = idx <= last ? bflo(w) : 0.f;
                    wb[k] = idx <= last ? bfhi(w) : 0.f;
                    ey[k] = eap[cl].x;
                    const float* xr = xw + (size_t)s[k] * 512 + c0;
                    x0[k] = *(const float2*)(xr + 128);
                    x1[k] = *(const float2*)(xr + 256);
                    x2[k] = *(const float2*)(xr + 384);
                }
#pragma unroll
                for (int k = 0; k < 8; ++k) {
                    float f0 = wa[k] * ey[k], f1 = wb[k] * ey[k];
                    a0 += f0 * x0[k].x; a1 += f0 * x1[k].x; a2 += f0 * x2[k].x;
                    a3 += f1 * x0[k].y; a4 += f1 * x1[k].y; a5 += f1 * x2[k].y;
                }
#pragma unroll
                for (int k = 0; k < 8; ++k) s[k] = sn[k];
            }
        } else {
            for (int g = beg; g < end; g += 8) {
                int sn[8];
#pragma unroll
                for (int k = 0; k < 8; ++k) {
                    int idx = g + 8 + k;
                    sn[k] = eis[idx <= last ? idx : last];
                }
                float wa[8], wb[8], ex[8], ey[8], ez[8];
                float2 x0[8], x1[8], x2[8];
#pragma unroll
                for (int k = 0; k < 8; ++k) {
                    int idx = g + k;
                    int cl = idx <= last ? idx : last;
                    uint32_t w = *(const uint32_t*)(plane + (size_t)cl * 128 + c0);
                    wa[k] = idx <= last ? bflo(w) : 0.f;
                    wb[k] = idx <= last ? bfhi(w) : 0.f;
                    float4 e = eap[cl];
                    ex[k] = e.y; ey[k] = e.z; ez[k] = e.w;
                    const float* xr = xw + (size_t)s[k] * 512 + c0;
                    x0[k] = *(const float2*)(xr + 128);
                    x1[k] = *(const float2*)(xr + 256);
                    x2[k] = *(const float2*)(xr + 384);
                }
#pragma unroll
                for (int k = 0; k < 8; ++k) {
                    float dta = x0[k].x * ex[k] + x1[k].x * ey[k] + x2[k].x * ez[k];
                    float dtb = x0[k].y * ex[k] + x1[k].y * ey[k] + x2[k].y * ez[k];
                    a0 += wa[k] * dta * 0.5773502691896258f;
                    a1 += wb[k] * dtb * 0.5773502691896258f;
                }
#pragma unroll
                for (int k = 0; k < 8; ++k) s[k] = sn[k];
            }
        }
    }

    unsigned short* mr = msgb + (size_t)n * 1024;
    if (j == 0) {
        *(uint32_t*)(mr + c0) = pack2(a0, a1);
    } else if (j == 1) {
        *(uint32_t*)(mr + 256 + c0)       = pack2(a0, a3);
        *(uint32_t*)(mr + 256 + 256 + c0) = pack2(a1, a4);
        *(uint32_t*)(mr + 256 + 512 + c0) = pack2(a2, a5);
    } else if (j == 2) {
        *(uint32_t*)(mr + 256 + 128 + c0)       = pack2(a0, a3);
        *(uint32_t*)(mr + 256 + 256 + 128 + c0) = pack2(a1, a4);
        *(uint32_t*)(mr + 256 + 512 + 128 + c0) = pack2(a2, a5);
    } else {
        *(uint32_t*)(mr + 128 + c0) = pack2(a0, a1);
    }
}

// ---------------------------------------------------------------------------
// k_out (R8, fused out0+out1): same 157-block grid, bodies unchanged; all
// A-loads (8 + 24 uint4) issued up front so the two serial A-latency
// exposures overlap. Saves 1 launch. Peak VGPR ~170 (no spill expected).
// ---------------------------------------------------------------------------
__global__ __launch_bounds__(256) void k_out(const unsigned short* __restrict__ msgb,
                                             const unsigned short* __restrict__ woT0,
                                             const unsigned short* __restrict__ woT1,
                                             float* __restrict__ out) {
    int wave = threadIdx.x >> 6, lane = threadIdx.x & 63;
    int wid = blockIdx.x * 4 + wave;
    if (wid >= NN / 16) return;
    int n0 = wid * 16;
    int lm = lane & 15, lq = lane >> 4;
    const unsigned short* ar = msgb + (size_t)(n0 + lm) * 1024 + lq * 8;

    uint4 A0[8];
#pragma unroll
    for (int kf = 0; kf < 8; ++kf) A0[kf] = *(const uint4*)(ar + kf * 32);
    uint4 A1[3][8];
#pragma unroll
    for (int m = 0; m < 3; ++m)
#pragma unroll
        for (int kf = 0; kf < 8; ++kf)
            A1[m][kf] = *(const uint4*)(ar + 256 + m * 256 + kf * 32);

    // ---- out0: o0 = msg0 @ Wo0 ----
    {
        const unsigned short* br = woT0 + lm * 256 + lq * 8;
        float* ob = out + (size_t)n0 * 512;
        for (int vt = 0; vt < 8; ++vt) {
            f32x4 acc = {0.f, 0.f, 0.f, 0.f};
#pragma unroll
            for (int kf = 0; kf < 8; ++kf) {
                uint4 b = *(const uint4*)(br + vt * 16 * 256 + kf * 32);
                acc = __builtin_amdgcn_mfma_f32_16x16x32_bf16(
                    __builtin_bit_cast(short8, A0[kf]), __builtin_bit_cast(short8, b), acc, 0, 0, 0);
            }
#pragma unroll
            for (int r = 0; r < 4; ++r)
                ob[(size_t)(lq * 4 + r) * 512 + vt * 16 + lm] = acc[r] * 0.00625f;
        }
    }

    // ---- out1: 3 GEMMs sharing B = woT1 -> out[n][128 + v*3 + m] ----
    {
        const unsigned short* br = woT1 + lm * 256 + lq * 8;
        float* ob = out + (size_t)n0 * 512 + 128;
        for (int vt = 0; vt < 8; ++vt) {
            f32x4 acc[3];
#pragma unroll
            for (int m = 0; m < 3; ++m) acc[m] = (f32x4){0.f, 0.f, 0.f, 0.f};
#pragma unroll
            for (int kf = 0; kf < 8; ++kf) {
                uint4 braw = *(const uint4*)(br + vt * 16 * 256 + kf * 32);
                short8 b = __builtin_bit_cast(short8, braw);
#pragma unroll
                for (int m = 0; m < 3; ++m)
                    acc[m] = __builtin_amdgcn_mfma_f32_16x16x32_bf16(
                        __builtin_bit_cast(short8, A1[m][kf]), b, acc[m], 0, 0, 0);
            }
            int vb = (vt * 16 + lm) * 3;
#pragma unroll
            for (int r = 0; r < 4; ++r) {
                float* o = ob + (size_t)(lq * 4 + r) * 512 + vb;
                o[0] = acc[0][r] * 0.00625f;
                o[1] = acc[1][r] * 0.00625f;
                o[2] = acc[2][r] * 0.00625f;
            }
        }
    }
}

// ---------------------------------------------------------------------------
extern "C" void kernel_launch(void* const* d_in, const int* in_sizes, int n_in,
                              void* d_out, int out_size, void* d_ws, size_t ws_size,
                              hipStream_t stream) {
    const float* nf  = (const float*)d_in[0];
    const float* ea  = (const float*)d_in[1];
    const float* ef  = (const float*)d_in[2];
    const int*   ei  = (const int*)d_in[3];
    const float* Wu0 = (const float*)d_in[4];
    const float* Wu1 = (const float*)d_in[5];
    const float* W1  = (const float*)d_in[6];
    const float* W2  = (const float*)d_in[7];
    const float* W3  = (const float*)d_in[8];
    const float* W4  = (const float*)d_in[9];
    const float* Wo0 = (const float*)d_in[10];
    const float* Wo1 = (const float*)d_in[11];
    float* out = (float*)d_out;
    char* ws = (char*)d_ws;

    // Layout (R3-proven, ws >= 226.2 MB):
    //   tpw planes [0, 163.84M)  xw [163.84M, 184.32M)  h3 [184.32M, 204.8M)
    //   msg [204.8M, 225.28M)  w4T [225.28M, +64K)  CSR ints  small weights.
    //   x0b/x1b alias tpw head (dead before k_tpw);
    //   woT0/woT1 + eis/eap alias h3 (dead after k_tpw) -> k_wt2/k_gather
    //   MUST stay after k_tpw.
    unsigned short* tpw  = (unsigned short*)ws;
    unsigned short* x0b  = (unsigned short*)ws;                 // 2.56 MB
    unsigned short* x1b  = (unsigned short*)(ws + 2560000);     // 7.68 MB
    float*          xw   = (float*)(ws + 163840000);
    unsigned short* h3w  = (unsigned short*)(ws + 184320000);
    unsigned short* woT0 = (unsigned short*)(ws + 184320000);
    unsigned short* woT1 = (unsigned short*)(ws + 184320000 + 65536);
    float4*         eap  = (float4*)(ws + 184320000 + 131072);            // NE*16B
    int*            eis  = (int*)(ws + 184320000 + 131072 + 2560000);     // NE*4B
    unsigned short* msgb = (unsigned short*)(ws + 204800000);
    unsigned short* w4T  = (unsigned short*)(ws + 225280000);
    int* ib     = (int*)(ws + 225280000 + 65536);
    int* counts = ib;                        // NN
    int* offs   = ib + 10240;                // NN+1
    int* cursor = ib + 20480;                // NN
    int* elist  = ib + 30720;                // NE
    unsigned short* w1Tp = (unsigned short*)(ws + 226108416);          // 64x32
    unsigned short* w2T  = (unsigned short*)(ws + 226108416 + 4096);   // 64x64
    unsigned short* w3T  = (unsigned short*)(ws + 226108416 + 12288);  // 64x64
    unsigned short* w0T  = (unsigned short*)(ws + 226128896);          // 128x128 (32KB)
    unsigned short* w1T  = (unsigned short*)(ws + 226161664);          // 128x128 (32KB)

    k_pre   <<<233, 256, 0, stream>>>(W1, W2, W3, Wu0, Wu1, W4,
                                      w1Tp, w2T, w3T, w0T, w1T, w4T, counts);
    k_prep2 <<<5625, 256, 0, stream>>>(nf, ei, x0b, x1b, counts);
    k_upg   <<<313, 256, 0, stream>>>(x0b, x1b, w0T, w1T, xw);
    k_mlp   <<<2500, 256, 0, stream>>>(ef, w1Tp, w2T, w3T, h3w);
    k_scan  <<<1, 1024, 0, stream>>>(counts, offs, cursor);
    k_fill  <<<625, 256, 0, stream>>>(ei, cursor, elist);
    k_tpw   <<<625, 256, 0, stream>>>(h3w, w4T, elist, tpw);
    k_wt2   <<<128, 256, 0, stream>>>(Wo0, Wo1, woT0, woT1);   // h3 dead now
    k_gather<<<625, 256, 0, stream>>>(ei, ea, elist, eis, eap);
    k_msg2  <<<NN, 256, 0, stream>>>(xw, tpw, eis, eap, offs, msgb);
    k_out   <<<157, 256, 0, stream>>>(msgb, woT0, woT1, out);
}